// Round 5
// baseline (396.772 us; speedup 1.0000x reference)
//
#include <hip/hip_runtime.h>
#include <cstdint>
#include <cstddef>

// Problem dims (fixed by reference): x [8,1024,1024] -> M=8192, dim=1024, hidden=4096
#define DIM   1024
#define HID   4096
#define MROWS 8192

typedef __attribute__((ext_vector_type(8))) __bf16 bf16x8;
typedef __attribute__((ext_vector_type(4))) float  f32x4;

__device__ __forceinline__ unsigned short f2bf(float f) {
  unsigned int u = __float_as_uint(f);
  u += 0x7fffu + ((u >> 16) & 1u);   // round-to-nearest-even
  return (unsigned short)(u >> 16);
}
__device__ __forceinline__ float bf2f(unsigned int lo16) {
  return __uint_as_float(lo16 << 16);
}

// tanh-form GELU: ~7 VALU instrs vs ~25 for erff; deviation from exact ~1e-3.
__device__ __forceinline__ float fast_gelu(float v) {
  float u = v * (0.79788456080286536f + 0.035677408136300125f * v * v);
  float e = __builtin_amdgcn_exp2f(u * 2.8853900817779268f);   // exp(2u)
  float r = __builtin_amdgcn_rcpf(e + 1.0f);
  return v - v * r;   // = v * e/(e+1) = 0.5 v (1+tanh(u))
}

// ---- async global->LDS, 16B per lane (m97 pattern) ----
__device__ __forceinline__ void gld16(const void* g, void* l) {
  auto* gp = reinterpret_cast<__attribute__((address_space(1))) unsigned int*>(
      reinterpret_cast<uintptr_t>(g));
  auto* lp = reinterpret_cast<__attribute__((address_space(3))) unsigned int*>(
      reinterpret_cast<uintptr_t>(l));
  __builtin_amdgcn_global_load_lds(gp, lp, 16, 0, 0);
}

// ---- block reduce (two values), 256 threads = 4 waves ----
__device__ __forceinline__ void block_reduce2(float& a, float& b, int tid) {
#pragma unroll
  for (int off = 32; off > 0; off >>= 1) {
    a += __shfl_xor(a, off, 64);
    b += __shfl_xor(b, off, 64);
  }
  __shared__ float red[8];
  if ((tid & 63) == 0) { red[tid >> 6] = a; red[4 + (tid >> 6)] = b; }
  __syncthreads();
  a = red[0] + red[1] + red[2] + red[3];
  b = red[4] + red[5] + red[6] + red[7];
}

// ---- stage 1: per-block partial sums of |w| (4096 floats per block) ----
// blocks 0..1023 -> w1, 1024..2047 -> w2 (both are 4M elements)
__global__ __launch_bounds__(256)
void absum_kernel(const float* __restrict__ w1, const float* __restrict__ w2,
                  float* __restrict__ part) {
  int tid = threadIdx.x;
  const float* w = (blockIdx.x < 1024) ? w1 : w2;
  int blk = blockIdx.x & 1023;
  const float4* base = (const float4*)w + (size_t)blk * 1024;
  float s = 0.f;
#pragma unroll
  for (int i = 0; i < 4; ++i) {
    float4 v = base[tid + i * 256];
    s += fabsf(v.x) + fabsf(v.y) + fabsf(v.z) + fabsf(v.w);
  }
#pragma unroll
  for (int off = 32; off > 0; off >>= 1) s += __shfl_xor(s, off, 64);
  __shared__ float red[4];
  if ((tid & 63) == 0) red[tid >> 6] = s;
  __syncthreads();
  if (tid == 0) part[blockIdx.x] = red[0] + red[1] + red[2] + red[3];
}

// ---- stage 2: final deterministic reduce -> clipped means for both weights ----
__global__ __launch_bounds__(256)
void final_reduce(const float* __restrict__ part, float* __restrict__ out) {
  int tid = threadIdx.x;
  float a = 0.f, b = 0.f;
  for (int i = tid; i < 1024; i += 256) { a += part[i]; b += part[1024 + i]; }
  block_reduce2(a, b, tid);
  if (tid == 0) {
    out[0] = fmaxf(a * (1.0f / 4194304.0f), 1e-5f);  // mean|w1| clipped
    out[1] = fmaxf(b * (1.0f / 4194304.0f), 1e-5f);  // mean|w2| clipped
  }
}

// ---- ternary quantize ----
// blocks 0..511:  q1 = clip(rint(w1/mean1)) as bf16 {-1,0,1}
// blocks 512..1023: q2 = clip(rint(w2/mean2)) * g2[k]  (LN2 gain folded into B)
__global__ __launch_bounds__(256)
void quant_kernel(const float* __restrict__ w1, unsigned short* __restrict__ q1,
                  const float* __restrict__ w2, unsigned short* __restrict__ q2,
                  const float* __restrict__ meanp, const float* __restrict__ g2) {
  const int n4 = 1048576;
  int bid = blockIdx.x;
  if (bid < 512) {
    float sc = 1.0f / meanp[0];
    int i = bid * 256 + threadIdx.x;
    for (; i < n4; i += 512 * 256) {
      float4 v = ((const float4*)w1)[i];
      float t0 = fminf(fmaxf(rintf(v.x * sc), -1.f), 1.f);
      float t1 = fminf(fmaxf(rintf(v.y * sc), -1.f), 1.f);
      float t2 = fminf(fmaxf(rintf(v.z * sc), -1.f), 1.f);
      float t3 = fminf(fmaxf(rintf(v.w * sc), -1.f), 1.f);
      uint2 r;
      r.x = (unsigned)f2bf(t0) | ((unsigned)f2bf(t1) << 16);
      r.y = (unsigned)f2bf(t2) | ((unsigned)f2bf(t3) << 16);
      ((uint2*)q1)[i] = r;
    }
  } else {
    float sc = 1.0f / meanp[1];
    int i = (bid - 512) * 256 + threadIdx.x;
    for (; i < n4; i += 512 * 256) {
      float4 v = ((const float4*)w2)[i];
      float4 gv = ((const float4*)g2)[i & 1023];   // w2 row = 4096 elems = 1024 f4
      float t0 = fminf(fmaxf(rintf(v.x * sc), -1.f), 1.f) * gv.x;
      float t1 = fminf(fmaxf(rintf(v.y * sc), -1.f), 1.f) * gv.y;
      float t2 = fminf(fmaxf(rintf(v.z * sc), -1.f), 1.f) * gv.z;
      float t3 = fminf(fmaxf(rintf(v.w * sc), -1.f), 1.f) * gv.w;
      uint2 r;
      r.x = (unsigned)f2bf(t0) | ((unsigned)f2bf(t1) << 16);
      r.y = (unsigned)f2bf(t2) | ((unsigned)f2bf(t3) << 16);
      ((uint2*)q2)[i] = r;
    }
  }
}

// ---- per-output-d vectors for the folded LN2 affine ----
// Sg[d] = mean2 * sum_k g2[k]*t2[d,k];  Cb[d] = mean2 * sum_k b2[k]*t2[d,k] + bias2[d]
__global__ __launch_bounds__(256)
void vec2_kernel(const float* __restrict__ w2, const float* __restrict__ g2,
                 const float* __restrict__ b2, const float* __restrict__ bias2,
                 const float* __restrict__ meanp,
                 float* __restrict__ Sg, float* __restrict__ Cb) {
  int d = blockIdx.x, tid = threadIdx.x;
  float sc = 1.0f / meanp[1];
  const float4* wr = (const float4*)(w2 + (size_t)d * 4096);
  const float4* g4 = (const float4*)g2;
  const float4* b4 = (const float4*)b2;
  float s1 = 0.f, s2 = 0.f;
#pragma unroll
  for (int i = 0; i < 4; ++i) {
    int idx = tid + 256 * i;
    float4 wv = wr[idx], gv = g4[idx], bv = b4[idx];
    float t;
    t = fminf(fmaxf(rintf(wv.x * sc), -1.f), 1.f); s1 += gv.x * t; s2 += bv.x * t;
    t = fminf(fmaxf(rintf(wv.y * sc), -1.f), 1.f); s1 += gv.y * t; s2 += bv.y * t;
    t = fminf(fmaxf(rintf(wv.z * sc), -1.f), 1.f); s1 += gv.z * t; s2 += bv.z * t;
    t = fminf(fmaxf(rintf(wv.w * sc), -1.f), 1.f); s1 += gv.w * t; s2 += bv.w * t;
  }
  block_reduce2(s1, s2, tid);
  if (tid == 0) {
    float m = meanp[1];
    Sg[d] = m * s1;
    Cb[d] = m * s2 + bias2[d];
  }
}

// ---- LN1: fp32 [8192,1024] -> bf16 normalized; also zeroes the h row-stats ----
__global__ __launch_bounds__(256)
void ln1_kernel(const float* __restrict__ x, const float* __restrict__ g,
                const float* __restrict__ b, unsigned short* __restrict__ out,
                float* __restrict__ stats) {
  int tid = threadIdx.x;
  if (tid == 0) {   // one row of stats per block; zero before GEMM1's atomics
    stats[2 * blockIdx.x]     = 0.f;
    stats[2 * blockIdx.x + 1] = 0.f;
  }
  const float4* xr = (const float4*)(x + (size_t)blockIdx.x * DIM);
  float4 v = xr[tid];
  float s  = v.x + v.y + v.z + v.w;
  float ss = v.x * v.x + v.y * v.y + v.z * v.z + v.w * v.w;
  block_reduce2(s, ss, tid);
  float mu  = s * (1.0f / DIM);
  float var = ss * (1.0f / DIM) - mu * mu;
  float rs  = rsqrtf(var + 1e-5f);
  float4 gg = ((const float4*)g)[tid];
  float4 bb = ((const float4*)b)[tid];
  uint2 r;
  r.x = (unsigned)f2bf((v.x - mu) * rs * gg.x + bb.x) |
        ((unsigned)f2bf((v.y - mu) * rs * gg.y + bb.y) << 16);
  r.y = (unsigned)f2bf((v.z - mu) * rs * gg.z + bb.z) |
        ((unsigned)f2bf((v.w - mu) * rs * gg.w + bb.w) << 16);
  *(uint2*)(out + (size_t)blockIdx.x * DIM + tid * 4) = r;
}

// ---- stats -> per-row (a_m, b_m): out = a_m*acc + b_m*Sg[d] + Cb[d] ----
__global__ __launch_bounds__(256)
void statsfix_kernel(const float* __restrict__ stats, const float* __restrict__ meanp,
                     float2* __restrict__ murs) {
  int m = blockIdx.x * 256 + threadIdx.x;
  float s  = stats[2 * m];
  float ss = stats[2 * m + 1];
  float mu  = s * (1.0f / HID);
  float var = ss * (1.0f / HID) - mu * mu;
  float rs  = rsqrtf(var + 1e-5f);
  float2 r;
  r.x = rs * meanp[1];   // multiplies acc (weights carry g2 but not mean2)
  r.y = -rs * mu;        // multiplies Sg[d] (mean2 already folded in)
  murs[m] = r;
}

// ---- GEMM C[m,n] = sum_k A[m,k]*B[n,k], fused epilogues ----
// A: bf16 [M,K] row-major; B: bf16 [N,K] row-major.
// 128x128 tile, BK=64, 256 thr = 4 waves (2x2 of 64x64), 16x16x32 bf16 MFMA.
// LDS XOR-granule swizzle: 16B chunk c of row r at position c^(r&7); applied
// to the global source chunk (global_load_lds dest is forced), undone at
// fragment read with a lane-constant XOR -> conflict-free (R2: 8.4M -> 0).
// XCD swizzle: each XCD (id%8 dispatch) owns 8 contiguous 128-row A-bands
// with all their column tiles -> A-band L2-resident (R4: FETCH 286->158MB).
// MODE 1 (GEMM1): v = gelu(acc*wscale + bias[n]); store bf16; accumulate
//   per-row sum/sumsq of v into stats[] via quad-shuffle + atomics (for LN2).
// MODE 0 (GEMM2): LN2 folded: out = a_m*acc + b_m*Sg[n] + Cb[n], fp32 store.
template <int MODE>
__global__ __launch_bounds__(256)
void gemm_bt(const unsigned short* __restrict__ A,
             const unsigned short* __restrict__ B,
             void* __restrict__ Cv,
             const float* __restrict__ wscale_ptr,
             const float* __restrict__ bias,
             float* __restrict__ stats,
             const float2* __restrict__ murs,
             const float* __restrict__ Sg,
             const float* __restrict__ Cb,
             int N, int K) {
  __shared__ unsigned short sA[128 * 64];
  __shared__ unsigned short sB[128 * 64];

  const int tid  = threadIdx.x;
  const int lane = tid & 63;
  const int wave = tid >> 6;
  const int wm   = wave & 1;   // 0..1
  const int wn   = wave >> 1;  // 0..1

  // XCD-aware remap of (bm, bn)
  const int nbx  = gridDim.x;                    // column tiles
  const int id   = blockIdx.y * nbx + blockIdx.x;
  const int xcd  = id & 7;
  const int slot = id >> 3;
  const int bandsPerXcd = gridDim.y >> 3;        // 8 for both GEMMs
  const int band = xcd * bandsPerXcd + slot / nbx;
  const int col  = slot - (slot / nbx) * nbx;
  const int bm   = band * 128;
  const int bn   = col * 128;

  // staging: thread t, round i: row 32i+(t>>3), stored chunk t&7,
  // global chunk (t&7)^((t>>3)&7)
  const int csw = (((tid & 7) ^ ((tid >> 3) & 7))) * 8;
  const unsigned short* Ab = A + (size_t)(bm + (tid >> 3)) * K + csw;
  const unsigned short* Bb = B + (size_t)(bn + (tid >> 3)) * K + csw;

  f32x4 acc[4][4] = {};

  // fragment read: row m = w*64 + i*16 + (lane&15); k-granule (half h) =
  // h*4 + (lane>>4); stored position = granule ^ (lane&7)
  const int rowA = (wm * 64 + (lane & 15)) * 64;
  const int rowB = (wn * 64 + (lane & 15)) * 64;
  const int p0 = ((0 + (lane >> 4)) ^ (lane & 7)) * 8;   // k-half 0
  const int p1 = ((4 + (lane >> 4)) ^ (lane & 7)) * 8;   // k-half 1

  for (int k0 = 0; k0 < K; k0 += 64) {
#pragma unroll
    for (int i = 0; i < 4; ++i) {
      gld16(Ab + (size_t)(32 * i) * K + k0, sA + i * 2048 + tid * 8);
      gld16(Bb + (size_t)(32 * i) * K + k0, sB + i * 2048 + tid * 8);
    }
    __syncthreads();

#pragma unroll
    for (int h = 0; h < 2; ++h) {
      const int ph = h ? p1 : p0;
      bf16x8 af[4], bfr[4];
#pragma unroll
      for (int i = 0; i < 4; ++i) af[i]  = *(const bf16x8*)(sA + rowA + i * 1024 + ph);
#pragma unroll
      for (int j = 0; j < 4; ++j) bfr[j] = *(const bf16x8*)(sB + rowB + j * 1024 + ph);
#pragma unroll
      for (int i = 0; i < 4; ++i)
#pragma unroll
        for (int j = 0; j < 4; ++j)
          acc[i][j] = __builtin_amdgcn_mfma_f32_16x16x32_bf16(af[i], bfr[j], acc[i][j], 0, 0, 0);
    }
    __syncthreads();
  }

  if (MODE == 1) {
    const float wscale = *wscale_ptr;
    float bv[4];
#pragma unroll
    for (int j = 0; j < 4; ++j) bv[j] = bias[bn + wn * 64 + j * 16 + (lane & 15)];
#pragma unroll
    for (int i = 0; i < 4; ++i) {
      const int m0 = bm + wm * 64 + i * 16 + ((lane >> 4) << 2);
      float s4[4] = {0.f, 0.f, 0.f, 0.f};
      float q4[4] = {0.f, 0.f, 0.f, 0.f};
#pragma unroll
      for (int j = 0; j < 4; ++j) {
        const int n = bn + wn * 64 + j * 16 + (lane & 15);
#pragma unroll
        for (int r = 0; r < 4; ++r) {
          float v = fast_gelu(acc[i][j][r] * wscale + bv[j]);
          s4[r] += v;
          q4[r] += v * v;
          ((unsigned short*)Cv)[(size_t)(m0 + r) * N + n] = f2bf(v);
        }
      }
      // reduce the 4 row-partials across the quad's 16 lanes, then atomics
#pragma unroll
      for (int r = 0; r < 4; ++r) {
#pragma unroll
        for (int msk = 1; msk < 16; msk <<= 1) {
          s4[r] += __shfl_xor(s4[r], msk, 64);
          q4[r] += __shfl_xor(q4[r], msk, 64);
        }
      }
      if ((lane & 15) == 0) {
#pragma unroll
        for (int r = 0; r < 4; ++r) {
          unsafeAtomicAdd(&stats[2 * (m0 + r)],     s4[r]);
          unsafeAtomicAdd(&stats[2 * (m0 + r) + 1], q4[r]);
        }
      }
    }
  } else {
    float sg[4], cb[4];
#pragma unroll
    for (int j = 0; j < 4; ++j) {
      const int n = bn + wn * 64 + j * 16 + (lane & 15);
      sg[j] = Sg[n];
      cb[j] = Cb[n];
    }
#pragma unroll
    for (int i = 0; i < 4; ++i) {
      const int m0 = bm + wm * 64 + i * 16 + ((lane >> 4) << 2);
#pragma unroll
      for (int r = 0; r < 4; ++r) {
        float2 ab = murs[m0 + r];
#pragma unroll
        for (int j = 0; j < 4; ++j) {
          const int n = bn + wn * 64 + j * 16 + (lane & 15);
          ((float*)Cv)[(size_t)(m0 + r) * N + n] = ab.x * acc[i][j][r] + ab.y * sg[j] + cb[j];
        }
      }
    }
  }
}

extern "C" void kernel_launch(void* const* d_in, const int* in_sizes, int n_in,
                              void* d_out, int out_size, void* d_ws, size_t ws_size,
                              hipStream_t stream) {
  const float* x     = (const float*)d_in[0];
  const float* g1    = (const float*)d_in[1];
  const float* b1v   = (const float*)d_in[2];
  const float* w1    = (const float*)d_in[3];
  const float* bias1 = (const float*)d_in[4];
  const float* g2    = (const float*)d_in[5];
  const float* b2v   = (const float*)d_in[6];
  const float* w2    = (const float*)d_in[7];
  const float* bias2 = (const float*)d_in[8];
  float* out = (float*)d_out;

  char* ws = (char*)d_ws;
  float* scal          = (float*)ws;                 // [0]=mean|w1| [1]=mean|w2| (clipped)
  float* part          = (float*)(ws + 64);          // 2048 partial sums
  unsigned short* q1   = (unsigned short*)(ws + 16384);   // 4096x1024 bf16
  unsigned short* q2   = q1 + 4194304;                    // 1024x4096 bf16 (g2-scaled)
  unsigned short* xn   = q2 + 4194304;                    // 8192x1024 bf16
  unsigned short* h    = xn + 8388608;                    // 8192x4096 bf16 (gelu out)
  float* stats         = (float*)(h + 33554432);          // 8192 x {sum, sumsq}
  float2* murs         = (float2*)(stats + 16384);        // 8192 x {a_m, b_m}
  float* Sg            = (float*)(murs + 8192);           // 1024
  float* Cb            = Sg + 1024;                       // 1024

  absum_kernel<<<2048, 256, 0, stream>>>(w1, w2, part);
  final_reduce<<<1, 256, 0, stream>>>(part, scal);
  quant_kernel<<<1024, 256, 0, stream>>>(w1, q1, w2, q2, scal, g2);
  vec2_kernel<<<1024, 256, 0, stream>>>(w2, g2, b2v, bias2, scal, Sg, Cb);
  ln1_kernel<<<8192, 256, 0, stream>>>(x, g1, b1v, xn, stats);
  gemm_bt<1><<<dim3(HID / 128, MROWS / 128), 256, 0, stream>>>(
      xn, q1, h, scal + 0, bias1, stats, nullptr, nullptr, nullptr, HID, DIM);
  statsfix_kernel<<<32, 256, 0, stream>>>(stats, scal, murs);
  gemm_bt<0><<<dim3(DIM / 128, MROWS / 128), 256, 0, stream>>>(
      h, q2, out, scal + 1, nullptr, nullptr, murs, Sg, Cb, DIM, HID);
}

// Round 7
// 318.828 us; speedup vs baseline: 1.2445x; 1.2445x over previous
//
#include <hip/hip_runtime.h>
#include <cstdint>
#include <cstddef>

// Problem dims (fixed by reference): x [8,1024,1024] -> M=8192, dim=1024, hidden=4096
#define DIM   1024
#define HID   4096
#define MROWS 8192

typedef __attribute__((ext_vector_type(8))) __bf16 bf16x8;
typedef __attribute__((ext_vector_type(4))) float  f32x4;

__device__ __forceinline__ unsigned short f2bf(float f) {
  unsigned int u = __float_as_uint(f);
  u += 0x7fffu + ((u >> 16) & 1u);   // round-to-nearest-even
  return (unsigned short)(u >> 16);
}
__device__ __forceinline__ float bf2f(unsigned int lo16) {
  return __uint_as_float(lo16 << 16);
}

// tanh-form GELU: ~7 VALU instrs vs ~25 for erff; deviation from exact ~1e-3.
__device__ __forceinline__ float fast_gelu(float v) {
  float u = v * (0.79788456080286536f + 0.035677408136300125f * v * v);
  float e = __builtin_amdgcn_exp2f(u * 2.8853900817779268f);   // exp(2u)
  float r = __builtin_amdgcn_rcpf(e + 1.0f);
  return v - v * r;   // = v * e/(e+1) = 0.5 v (1+tanh(u))
}

// ---- async global->LDS, 16B per lane (m97 pattern) ----
__device__ __forceinline__ void gld16(const void* g, void* l) {
  auto* gp = reinterpret_cast<__attribute__((address_space(1))) unsigned int*>(
      reinterpret_cast<uintptr_t>(g));
  auto* lp = reinterpret_cast<__attribute__((address_space(3))) unsigned int*>(
      reinterpret_cast<uintptr_t>(l));
  __builtin_amdgcn_global_load_lds(gp, lp, 16, 0, 0);
}

// ---- block reduce (two values), 256 threads = 4 waves ----
__device__ __forceinline__ void block_reduce2(float& a, float& b, int tid) {
#pragma unroll
  for (int off = 32; off > 0; off >>= 1) {
    a += __shfl_xor(a, off, 64);
    b += __shfl_xor(b, off, 64);
  }
  __shared__ float red[8];
  if ((tid & 63) == 0) { red[tid >> 6] = a; red[4 + (tid >> 6)] = b; }
  __syncthreads();
  a = red[0] + red[1] + red[2] + red[3];
  b = red[4] + red[5] + red[6] + red[7];
}

// ---- stage 1: per-block partial sums of |w| (4096 floats per block) ----
// blocks 0..1023 -> w1, 1024..2047 -> w2 (both are 4M elements)
__global__ __launch_bounds__(256)
void absum_kernel(const float* __restrict__ w1, const float* __restrict__ w2,
                  float* __restrict__ part) {
  int tid = threadIdx.x;
  const float* w = (blockIdx.x < 1024) ? w1 : w2;
  int blk = blockIdx.x & 1023;
  const float4* base = (const float4*)w + (size_t)blk * 1024;
  float s = 0.f;
#pragma unroll
  for (int i = 0; i < 4; ++i) {
    float4 v = base[tid + i * 256];
    s += fabsf(v.x) + fabsf(v.y) + fabsf(v.z) + fabsf(v.w);
  }
#pragma unroll
  for (int off = 32; off > 0; off >>= 1) s += __shfl_xor(s, off, 64);
  __shared__ float red[4];
  if ((tid & 63) == 0) red[tid >> 6] = s;
  __syncthreads();
  if (tid == 0) part[blockIdx.x] = red[0] + red[1] + red[2] + red[3];
}

// ---- stage 2: final deterministic reduce -> clipped means for both weights ----
__global__ __launch_bounds__(256)
void final_reduce(const float* __restrict__ part, float* __restrict__ out) {
  int tid = threadIdx.x;
  float a = 0.f, b = 0.f;
  for (int i = tid; i < 1024; i += 256) { a += part[i]; b += part[1024 + i]; }
  block_reduce2(a, b, tid);
  if (tid == 0) {
    out[0] = fmaxf(a * (1.0f / 4194304.0f), 1e-5f);  // mean|w1| clipped
    out[1] = fmaxf(b * (1.0f / 4194304.0f), 1e-5f);  // mean|w2| clipped
  }
}

// ---- ternary quantize ----
// blocks 0..511:  q1 = clip(rint(w1/mean1)) as bf16 {-1,0,1}
// blocks 512..1023: q2 = clip(rint(w2/mean2)) * g2[k]  (LN2 gain folded into B)
__global__ __launch_bounds__(256)
void quant_kernel(const float* __restrict__ w1, unsigned short* __restrict__ q1,
                  const float* __restrict__ w2, unsigned short* __restrict__ q2,
                  const float* __restrict__ meanp, const float* __restrict__ g2) {
  const int n4 = 1048576;
  int bid = blockIdx.x;
  if (bid < 512) {
    float sc = 1.0f / meanp[0];
    int i = bid * 256 + threadIdx.x;
    for (; i < n4; i += 512 * 256) {
      float4 v = ((const float4*)w1)[i];
      float t0 = fminf(fmaxf(rintf(v.x * sc), -1.f), 1.f);
      float t1 = fminf(fmaxf(rintf(v.y * sc), -1.f), 1.f);
      float t2 = fminf(fmaxf(rintf(v.z * sc), -1.f), 1.f);
      float t3 = fminf(fmaxf(rintf(v.w * sc), -1.f), 1.f);
      uint2 r;
      r.x = (unsigned)f2bf(t0) | ((unsigned)f2bf(t1) << 16);
      r.y = (unsigned)f2bf(t2) | ((unsigned)f2bf(t3) << 16);
      ((uint2*)q1)[i] = r;
    }
  } else {
    float sc = 1.0f / meanp[1];
    int i = (bid - 512) * 256 + threadIdx.x;
    for (; i < n4; i += 512 * 256) {
      float4 v = ((const float4*)w2)[i];
      float4 gv = ((const float4*)g2)[i & 1023];   // w2 row = 4096 elems = 1024 f4
      float t0 = fminf(fmaxf(rintf(v.x * sc), -1.f), 1.f) * gv.x;
      float t1 = fminf(fmaxf(rintf(v.y * sc), -1.f), 1.f) * gv.y;
      float t2 = fminf(fmaxf(rintf(v.z * sc), -1.f), 1.f) * gv.z;
      float t3 = fminf(fmaxf(rintf(v.w * sc), -1.f), 1.f) * gv.w;
      uint2 r;
      r.x = (unsigned)f2bf(t0) | ((unsigned)f2bf(t1) << 16);
      r.y = (unsigned)f2bf(t2) | ((unsigned)f2bf(t3) << 16);
      ((uint2*)q2)[i] = r;
    }
  }
}

// ---- per-output-d vectors for the folded LN2 affine ----
// Sg[d] = mean2 * sum_k g2[k]*t2[d,k];  Cb[d] = mean2 * sum_k b2[k]*t2[d,k] + bias2[d]
__global__ __launch_bounds__(256)
void vec2_kernel(const float* __restrict__ w2, const float* __restrict__ g2,
                 const float* __restrict__ b2, const float* __restrict__ bias2,
                 const float* __restrict__ meanp,
                 float* __restrict__ Sg, float* __restrict__ Cb) {
  int d = blockIdx.x, tid = threadIdx.x;
  float sc = 1.0f / meanp[1];
  const float4* wr = (const float4*)(w2 + (size_t)d * 4096);
  const float4* g4 = (const float4*)g2;
  const float4* b4 = (const float4*)b2;
  float s1 = 0.f, s2 = 0.f;
#pragma unroll
  for (int i = 0; i < 4; ++i) {
    int idx = tid + 256 * i;
    float4 wv = wr[idx], gv = g4[idx], bv = b4[idx];
    float t;
    t = fminf(fmaxf(rintf(wv.x * sc), -1.f), 1.f); s1 += gv.x * t; s2 += bv.x * t;
    t = fminf(fmaxf(rintf(wv.y * sc), -1.f), 1.f); s1 += gv.y * t; s2 += bv.y * t;
    t = fminf(fmaxf(rintf(wv.z * sc), -1.f), 1.f); s1 += gv.z * t; s2 += bv.z * t;
    t = fminf(fmaxf(rintf(wv.w * sc), -1.f), 1.f); s1 += gv.w * t; s2 += bv.w * t;
  }
  block_reduce2(s1, s2, tid);
  if (tid == 0) {
    float m = meanp[1];
    Sg[d] = m * s1;
    Cb[d] = m * s2 + bias2[d];
  }
}

// ---- LN1: fp32 [8192,1024] -> bf16 normalized ----
__global__ __launch_bounds__(256)
void ln1_kernel(const float* __restrict__ x, const float* __restrict__ g,
                const float* __restrict__ b, unsigned short* __restrict__ out) {
  int tid = threadIdx.x;
  const float4* xr = (const float4*)(x + (size_t)blockIdx.x * DIM);
  float4 v = xr[tid];
  float s  = v.x + v.y + v.z + v.w;
  float ss = v.x * v.x + v.y * v.y + v.z * v.z + v.w * v.w;
  block_reduce2(s, ss, tid);
  float mu  = s * (1.0f / DIM);
  float var = ss * (1.0f / DIM) - mu * mu;
  float rs  = rsqrtf(var + 1e-5f);
  float4 gg = ((const float4*)g)[tid];
  float4 bb = ((const float4*)b)[tid];
  uint2 r;
  r.x = (unsigned)f2bf((v.x - mu) * rs * gg.x + bb.x) |
        ((unsigned)f2bf((v.y - mu) * rs * gg.y + bb.y) << 16);
  r.y = (unsigned)f2bf((v.z - mu) * rs * gg.z + bb.z) |
        ((unsigned)f2bf((v.w - mu) * rs * gg.w + bb.w) << 16);
  *(uint2*)(out + (size_t)blockIdx.x * DIM + tid * 4) = r;
}

// ---- reduce per-block partial stats -> per-row (a_m, b_m) ----
// hpart layout: [m][slot][2] floats, slot = col*2 + wn (64 slots per row:
// 32 column-blocks x 2 column-waves). Every slot written exactly once.
// out = a_m*acc + b_m*Sg[d] + Cb[d]
__global__ __launch_bounds__(256)
void statsfix_kernel(const float* __restrict__ hpart, const float* __restrict__ meanp,
                     float2* __restrict__ murs) {
  int m = blockIdx.x * 256 + threadIdx.x;
  const float4* p = (const float4*)(hpart + (size_t)m * 128);
  float s = 0.f, q = 0.f;
#pragma unroll
  for (int i = 0; i < 32; ++i) {
    float4 v = p[i];
    s += v.x + v.z;
    q += v.y + v.w;
  }
  float mu  = s * (1.0f / HID);
  float var = q * (1.0f / HID) - mu * mu;
  float rs  = rsqrtf(var + 1e-5f);
  float2 r;
  r.x = rs * meanp[1];   // multiplies acc (weights carry g2 but not mean2)
  r.y = -rs * mu;        // multiplies Sg[d] (mean2 already folded in)
  murs[m] = r;
}

// ---- GEMM C[m,n] = sum_k A[m,k]*B[n,k], fused epilogues ----
// A: bf16 [M,K] row-major; B: bf16 [N,K] row-major.
// 128x128 tile, BK=64, 256 thr = 4 waves (2x2 of 64x64), 16x16x32 bf16 MFMA.
// LDS XOR-granule swizzle: 16B chunk c of row r at position c^(r&7); applied
// to the global source chunk (global_load_lds dest is forced), undone at
// fragment read with a lane-constant XOR -> conflict-free (R2: 8.4M -> 0).
// XCD swizzle: each XCD (id%8 dispatch) owns 8 contiguous 128-row A-bands
// with all their column tiles -> A-band L2-resident (R4: FETCH 286->158MB).
// MODE 1 (GEMM1): v = gelu(acc*wscale + bias[n]); store bf16; quad-shuffle
//   row sums/sumsqs, store to PRIVATE slot hpart[m][col*2+wn] (plain stores;
//   R5: contended cross-XCD atomics serialize ~300ns each. R6 bug: wn=0 and
//   wn=1 waves cover different column halves and MUST get separate slots).
// MODE 0 (GEMM2): LN2 folded: out = a_m*acc + b_m*Sg[n] + Cb[n], fp32 store.
template <int MODE>
__global__ __launch_bounds__(256)
void gemm_bt(const unsigned short* __restrict__ A,
             const unsigned short* __restrict__ B,
             void* __restrict__ Cv,
             const float* __restrict__ wscale_ptr,
             const float* __restrict__ bias,
             float* __restrict__ hpart,
             const float2* __restrict__ murs,
             const float* __restrict__ Sg,
             const float* __restrict__ Cb,
             int N, int K) {
  __shared__ unsigned short sA[128 * 64];
  __shared__ unsigned short sB[128 * 64];

  const int tid  = threadIdx.x;
  const int lane = tid & 63;
  const int wave = tid >> 6;
  const int wm   = wave & 1;   // 0..1
  const int wn   = wave >> 1;  // 0..1

  // XCD-aware remap of (bm, bn)
  const int nbx  = gridDim.x;                    // column tiles
  const int id   = blockIdx.y * nbx + blockIdx.x;
  const int xcd  = id & 7;
  const int slot = id >> 3;
  const int bandsPerXcd = gridDim.y >> 3;        // 8 for both GEMMs
  const int band = xcd * bandsPerXcd + slot / nbx;
  const int col  = slot - (slot / nbx) * nbx;
  const int bm   = band * 128;
  const int bn   = col * 128;

  // staging: thread t, round i: row 32i+(t>>3), stored chunk t&7,
  // global chunk (t&7)^((t>>3)&7)
  const int csw = (((tid & 7) ^ ((tid >> 3) & 7))) * 8;
  const unsigned short* Ab = A + (size_t)(bm + (tid >> 3)) * K + csw;
  const unsigned short* Bb = B + (size_t)(bn + (tid >> 3)) * K + csw;

  f32x4 acc[4][4] = {};

  // fragment read: row m = w*64 + i*16 + (lane&15); k-granule (half h) =
  // h*4 + (lane>>4); stored position = granule ^ (lane&7)
  const int rowA = (wm * 64 + (lane & 15)) * 64;
  const int rowB = (wn * 64 + (lane & 15)) * 64;
  const int p0 = ((0 + (lane >> 4)) ^ (lane & 7)) * 8;   // k-half 0
  const int p1 = ((4 + (lane >> 4)) ^ (lane & 7)) * 8;   // k-half 1

  for (int k0 = 0; k0 < K; k0 += 64) {
#pragma unroll
    for (int i = 0; i < 4; ++i) {
      gld16(Ab + (size_t)(32 * i) * K + k0, sA + i * 2048 + tid * 8);
      gld16(Bb + (size_t)(32 * i) * K + k0, sB + i * 2048 + tid * 8);
    }
    __syncthreads();

#pragma unroll
    for (int h = 0; h < 2; ++h) {
      const int ph = h ? p1 : p0;
      bf16x8 af[4], bfr[4];
#pragma unroll
      for (int i = 0; i < 4; ++i) af[i]  = *(const bf16x8*)(sA + rowA + i * 1024 + ph);
#pragma unroll
      for (int j = 0; j < 4; ++j) bfr[j] = *(const bf16x8*)(sB + rowB + j * 1024 + ph);
#pragma unroll
      for (int i = 0; i < 4; ++i)
#pragma unroll
        for (int j = 0; j < 4; ++j)
          acc[i][j] = __builtin_amdgcn_mfma_f32_16x16x32_bf16(af[i], bfr[j], acc[i][j], 0, 0, 0);
    }
    __syncthreads();
  }

  if (MODE == 1) {
    const float wscale = *wscale_ptr;
    float bv[4];
#pragma unroll
    for (int j = 0; j < 4; ++j) bv[j] = bias[bn + wn * 64 + j * 16 + (lane & 15)];
#pragma unroll
    for (int i = 0; i < 4; ++i) {
      const int m0 = bm + wm * 64 + i * 16 + ((lane >> 4) << 2);
      float s4[4] = {0.f, 0.f, 0.f, 0.f};
      float q4[4] = {0.f, 0.f, 0.f, 0.f};
#pragma unroll
      for (int j = 0; j < 4; ++j) {
        const int n = bn + wn * 64 + j * 16 + (lane & 15);
#pragma unroll
        for (int r = 0; r < 4; ++r) {
          float v = fast_gelu(acc[i][j][r] * wscale + bv[j]);
          s4[r] += v;
          q4[r] += v * v;
          ((unsigned short*)Cv)[(size_t)(m0 + r) * N + n] = f2bf(v);
        }
      }
      // reduce the 4 row-partials across the quad's 16 lanes
#pragma unroll
      for (int r = 0; r < 4; ++r) {
#pragma unroll
        for (int msk = 1; msk < 16; msk <<= 1) {
          s4[r] += __shfl_xor(s4[r], msk, 64);
          q4[r] += __shfl_xor(q4[r], msk, 64);
        }
      }
      if ((lane & 15) == 0) {
        // private slot per (row, col-block, wn): exactly one writer each
#pragma unroll
        for (int r = 0; r < 4; ++r) {
          float2* dst = (float2*)(hpart + ((size_t)(m0 + r) * 64 + col * 2 + wn) * 2);
          *dst = make_float2(s4[r], q4[r]);
        }
      }
    }
  } else {
    float sg[4], cb[4];
#pragma unroll
    for (int j = 0; j < 4; ++j) {
      const int n = bn + wn * 64 + j * 16 + (lane & 15);
      sg[j] = Sg[n];
      cb[j] = Cb[n];
    }
#pragma unroll
    for (int i = 0; i < 4; ++i) {
      const int m0 = bm + wm * 64 + i * 16 + ((lane >> 4) << 2);
#pragma unroll
      for (int r = 0; r < 4; ++r) {
        float2 ab = murs[m0 + r];
#pragma unroll
        for (int j = 0; j < 4; ++j) {
          const int n = bn + wn * 64 + j * 16 + (lane & 15);
          ((float*)Cv)[(size_t)(m0 + r) * N + n] = ab.x * acc[i][j][r] + ab.y * sg[j] + cb[j];
        }
      }
    }
  }
}

extern "C" void kernel_launch(void* const* d_in, const int* in_sizes, int n_in,
                              void* d_out, int out_size, void* d_ws, size_t ws_size,
                              hipStream_t stream) {
  const float* x     = (const float*)d_in[0];
  const float* g1    = (const float*)d_in[1];
  const float* b1v   = (const float*)d_in[2];
  const float* w1    = (const float*)d_in[3];
  const float* bias1 = (const float*)d_in[4];
  const float* g2    = (const float*)d_in[5];
  const float* b2v   = (const float*)d_in[6];
  const float* w2    = (const float*)d_in[7];
  const float* bias2 = (const float*)d_in[8];
  float* out = (float*)d_out;

  char* ws = (char*)d_ws;
  float* scal          = (float*)ws;                 // [0]=mean|w1| [1]=mean|w2| (clipped)
  float* part          = (float*)(ws + 64);          // 2048 partial sums
  unsigned short* q1   = (unsigned short*)(ws + 16384);   // 4096x1024 bf16
  unsigned short* q2   = q1 + 4194304;                    // 1024x4096 bf16 (g2-scaled)
  unsigned short* xn   = q2 + 4194304;                    // 8192x1024 bf16
  unsigned short* h    = xn + 8388608;                    // 8192x4096 bf16 (gelu out)
  float* hpart         = (float*)(h + 33554432);          // [8192][64][2] = 4 MB
  float2* murs         = (float2*)(hpart + 1048576);      // 8192 x {a_m, b_m}
  float* Sg            = (float*)(murs + 8192);           // 1024
  float* Cb            = Sg + 1024;                       // 1024

  absum_kernel<<<2048, 256, 0, stream>>>(w1, w2, part);
  final_reduce<<<1, 256, 0, stream>>>(part, scal);
  quant_kernel<<<1024, 256, 0, stream>>>(w1, q1, w2, q2, scal, g2);
  vec2_kernel<<<1024, 256, 0, stream>>>(w2, g2, b2v, bias2, scal, Sg, Cb);
  ln1_kernel<<<8192, 256, 0, stream>>>(x, g1, b1v, xn);
  gemm_bt<1><<<dim3(HID / 128, MROWS / 128), 256, 0, stream>>>(
      xn, q1, h, scal + 0, bias1, hpart, nullptr, nullptr, nullptr, HID, DIM);
  statsfix_kernel<<<32, 256, 0, stream>>>(hpart, scal, murs);
  gemm_bt<0><<<dim3(DIM / 128, MROWS / 128), 256, 0, stream>>>(
      h, q2, out, scal + 1, nullptr, nullptr, murs, Sg, Cb, DIM, HID);
}

// Round 8
// 292.549 us; speedup vs baseline: 1.3563x; 1.0898x over previous
//
#include <hip/hip_runtime.h>
#include <cstdint>
#include <cstddef>

// Problem dims (fixed by reference): x [8,1024,1024] -> M=8192, dim=1024, hidden=4096
#define DIM   1024
#define HID   4096
#define MROWS 8192

typedef __attribute__((ext_vector_type(8))) __bf16 bf16x8;
typedef __attribute__((ext_vector_type(4))) float  f32x4;

__device__ __forceinline__ unsigned short f2bf(float f) {
  unsigned int u = __float_as_uint(f);
  u += 0x7fffu + ((u >> 16) & 1u);   // round-to-nearest-even
  return (unsigned short)(u >> 16);
}
__device__ __forceinline__ float bf2f(unsigned int lo16) {
  return __uint_as_float(lo16 << 16);
}

// tanh-form GELU: ~7 VALU instrs vs ~25 for erff; deviation from exact ~1e-3.
__device__ __forceinline__ float fast_gelu(float v) {
  float u = v * (0.79788456080286536f + 0.035677408136300125f * v * v);
  float e = __builtin_amdgcn_exp2f(u * 2.8853900817779268f);   // exp(2u)
  float r = __builtin_amdgcn_rcpf(e + 1.0f);
  return v - v * r;   // = v * e/(e+1) = 0.5 v (1+tanh(u))
}

// ---- async global->LDS, 16B per lane (m97 pattern) ----
__device__ __forceinline__ void gld16(const void* g, void* l) {
  auto* gp = reinterpret_cast<__attribute__((address_space(1))) unsigned int*>(
      reinterpret_cast<uintptr_t>(g));
  auto* lp = reinterpret_cast<__attribute__((address_space(3))) unsigned int*>(
      reinterpret_cast<uintptr_t>(l));
  __builtin_amdgcn_global_load_lds(gp, lp, 16, 0, 0);
}

// ---- block reduce (two values), 256 threads = 4 waves ----
__device__ __forceinline__ void block_reduce2(float& a, float& b, int tid) {
#pragma unroll
  for (int off = 32; off > 0; off >>= 1) {
    a += __shfl_xor(a, off, 64);
    b += __shfl_xor(b, off, 64);
  }
  __shared__ float red[8];
  if ((tid & 63) == 0) { red[tid >> 6] = a; red[4 + (tid >> 6)] = b; }
  __syncthreads();
  a = red[0] + red[1] + red[2] + red[3];
  b = red[4] + red[5] + red[6] + red[7];
}

// ---- stage 1: per-block partial sums of |w| (4096 floats per block) ----
// blocks 0..1023 -> w1, 1024..2047 -> w2 (both are 4M elements)
__global__ __launch_bounds__(256)
void absum_kernel(const float* __restrict__ w1, const float* __restrict__ w2,
                  float* __restrict__ part) {
  int tid = threadIdx.x;
  const float* w = (blockIdx.x < 1024) ? w1 : w2;
  int blk = blockIdx.x & 1023;
  const float4* base = (const float4*)w + (size_t)blk * 1024;
  float s = 0.f;
#pragma unroll
  for (int i = 0; i < 4; ++i) {
    float4 v = base[tid + i * 256];
    s += fabsf(v.x) + fabsf(v.y) + fabsf(v.z) + fabsf(v.w);
  }
#pragma unroll
  for (int off = 32; off > 0; off >>= 1) s += __shfl_xor(s, off, 64);
  __shared__ float red[4];
  if ((tid & 63) == 0) red[tid >> 6] = s;
  __syncthreads();
  if (tid == 0) part[blockIdx.x] = red[0] + red[1] + red[2] + red[3];
}

// ---- stage 2: final deterministic reduce -> clipped means for both weights ----
__global__ __launch_bounds__(256)
void final_reduce(const float* __restrict__ part, float* __restrict__ out) {
  int tid = threadIdx.x;
  float a = 0.f, b = 0.f;
  for (int i = tid; i < 1024; i += 256) { a += part[i]; b += part[1024 + i]; }
  block_reduce2(a, b, tid);
  if (tid == 0) {
    out[0] = fmaxf(a * (1.0f / 4194304.0f), 1e-5f);  // mean|w1| clipped
    out[1] = fmaxf(b * (1.0f / 4194304.0f), 1e-5f);  // mean|w2| clipped
  }
}

// ---- ternary quantize + folded-LN2 weight vectors, one kernel ----
// blocks 0..511:    q1 = clip(rint(w1/mean1)) as bf16 {-1,0,1} (grid-stride)
// blocks 512..1535: block owns w2 row d = bid-512:
//   q2[d][k] = clip(rint(w2/mean2)) * g2[k]   (LN2 gain folded into B)
//   Sg[d] = mean2 * sum_k g2[k]*t;  Cb[d] = mean2 * sum_k b2[k]*t + bias2[d]
__global__ __launch_bounds__(256)
void quant_kernel(const float* __restrict__ w1, unsigned short* __restrict__ q1,
                  const float* __restrict__ w2, unsigned short* __restrict__ q2,
                  const float* __restrict__ meanp, const float* __restrict__ g2,
                  const float* __restrict__ b2, const float* __restrict__ bias2,
                  float* __restrict__ Sg, float* __restrict__ Cb) {
  int bid = blockIdx.x, tid = threadIdx.x;
  if (bid < 512) {
    const int n4 = 1048576;
    float sc = 1.0f / meanp[0];
    int i = bid * 256 + tid;
    for (; i < n4; i += 512 * 256) {
      float4 v = ((const float4*)w1)[i];
      float t0 = fminf(fmaxf(rintf(v.x * sc), -1.f), 1.f);
      float t1 = fminf(fmaxf(rintf(v.y * sc), -1.f), 1.f);
      float t2 = fminf(fmaxf(rintf(v.z * sc), -1.f), 1.f);
      float t3 = fminf(fmaxf(rintf(v.w * sc), -1.f), 1.f);
      uint2 r;
      r.x = (unsigned)f2bf(t0) | ((unsigned)f2bf(t1) << 16);
      r.y = (unsigned)f2bf(t2) | ((unsigned)f2bf(t3) << 16);
      ((uint2*)q1)[i] = r;
    }
  } else {
    const int d = bid - 512;
    float sc = 1.0f / meanp[1];
    const float4* wr = (const float4*)(w2 + (size_t)d * HID);
    const float4* g4 = (const float4*)g2;
    const float4* b4 = (const float4*)b2;
    uint2* qr = (uint2*)(q2 + (size_t)d * HID);
    float s1 = 0.f, s2 = 0.f;
#pragma unroll
    for (int i = 0; i < 4; ++i) {
      int idx = tid + 256 * i;
      float4 wv = wr[idx], gv = g4[idx], bv = b4[idx];
      float t0 = fminf(fmaxf(rintf(wv.x * sc), -1.f), 1.f);
      float t1 = fminf(fmaxf(rintf(wv.y * sc), -1.f), 1.f);
      float t2 = fminf(fmaxf(rintf(wv.z * sc), -1.f), 1.f);
      float t3 = fminf(fmaxf(rintf(wv.w * sc), -1.f), 1.f);
      s1 += gv.x * t0 + gv.y * t1 + gv.z * t2 + gv.w * t3;
      s2 += bv.x * t0 + bv.y * t1 + bv.z * t2 + bv.w * t3;
      uint2 r;
      r.x = (unsigned)f2bf(t0 * gv.x) | ((unsigned)f2bf(t1 * gv.y) << 16);
      r.y = (unsigned)f2bf(t2 * gv.z) | ((unsigned)f2bf(t3 * gv.w) << 16);
      qr[idx] = r;
    }
    block_reduce2(s1, s2, tid);
    if (tid == 0) {
      float m = meanp[1];
      Sg[d] = m * s1;
      Cb[d] = m * s2 + bias2[d];
    }
  }
}

// ---- LN1: fp32 [8192,1024] -> bf16 normalized ----
__global__ __launch_bounds__(256)
void ln1_kernel(const float* __restrict__ x, const float* __restrict__ g,
                const float* __restrict__ b, unsigned short* __restrict__ out) {
  int tid = threadIdx.x;
  const float4* xr = (const float4*)(x + (size_t)blockIdx.x * DIM);
  float4 v = xr[tid];
  float s  = v.x + v.y + v.z + v.w;
  float ss = v.x * v.x + v.y * v.y + v.z * v.z + v.w * v.w;
  block_reduce2(s, ss, tid);
  float mu  = s * (1.0f / DIM);
  float var = ss * (1.0f / DIM) - mu * mu;
  float rs  = rsqrtf(var + 1e-5f);
  float4 gg = ((const float4*)g)[tid];
  float4 bb = ((const float4*)b)[tid];
  uint2 r;
  r.x = (unsigned)f2bf((v.x - mu) * rs * gg.x + bb.x) |
        ((unsigned)f2bf((v.y - mu) * rs * gg.y + bb.y) << 16);
  r.y = (unsigned)f2bf((v.z - mu) * rs * gg.z + bb.z) |
        ((unsigned)f2bf((v.w - mu) * rs * gg.w + bb.w) << 16);
  *(uint2*)(out + (size_t)blockIdx.x * DIM + tid * 4) = r;
}

// ---- row stats of h (read-only) -> per-row (a_m, b_m) for folded LN2 ----
// One block per row: read 4096 bf16 (8 KB), block-reduce, write murs[m].
// Replaces R7's in-GEMM shuffle cascade (which cost GEMM1 +25us) and the
// old ln2 pass (which wrote 64MB back). out = a_m*acc + b_m*Sg[d] + Cb[d].
__global__ __launch_bounds__(256)
void rowstats_kernel(const unsigned short* __restrict__ h,
                     const float* __restrict__ meanp,
                     float2* __restrict__ murs) {
  int tid = threadIdx.x;
  const unsigned short* hr = h + (size_t)blockIdx.x * HID;
  uint4 pa = ((const uint4*)hr)[tid];
  uint4 pb = ((const uint4*)hr)[tid + 256];
  float s = 0.f, ss = 0.f;
  {
    const unsigned int* pu = (const unsigned int*)&pa;
#pragma unroll
    for (int j = 0; j < 4; ++j) {
      float lo = bf2f(pu[j] & 0xffffu);
      float hi = __uint_as_float(pu[j] & 0xffff0000u);
      s += lo + hi; ss += lo * lo + hi * hi;
    }
    pu = (const unsigned int*)&pb;
#pragma unroll
    for (int j = 0; j < 4; ++j) {
      float lo = bf2f(pu[j] & 0xffffu);
      float hi = __uint_as_float(pu[j] & 0xffff0000u);
      s += lo + hi; ss += lo * lo + hi * hi;
    }
  }
  block_reduce2(s, ss, tid);
  if (tid == 0) {
    float mu  = s * (1.0f / HID);
    float var = ss * (1.0f / HID) - mu * mu;
    float rs  = rsqrtf(var + 1e-5f);
    murs[blockIdx.x] = make_float2(rs * meanp[1], -rs * mu);
  }
}

// ---- GEMM C[m,n] = sum_k A[m,k]*B[n,k], fused epilogues ----
// A: bf16 [M,K] row-major; B: bf16 [N,K] row-major.
// 128x128 tile, BK=64, 256 thr = 4 waves (2x2 of 64x64), 16x16x32 bf16 MFMA.
// LDS XOR-granule swizzle: 16B chunk c of row r at position c^(r&7); applied
// to the global source chunk (global_load_lds dest is forced), undone at
// fragment read with a lane-constant XOR -> conflict-free (R2: 8.4M -> 0).
// XCD swizzle: each XCD (id%8 dispatch) owns 8 contiguous 128-row A-bands
// with all their column tiles -> A-band L2-resident (R4: FETCH 286->158MB).
// MODE 1 (GEMM1): v = gelu(acc*wscale + bias[n]); store bf16. (Stats moved
//   OUT of this epilogue: R7 showed the shuffle cascade cost +25us here.)
// MODE 0 (GEMM2): LN2 folded: out = a_m*acc + b_m*Sg[n] + Cb[n], fp32 store.
template <int MODE>
__global__ __launch_bounds__(256)
void gemm_bt(const unsigned short* __restrict__ A,
             const unsigned short* __restrict__ B,
             void* __restrict__ Cv,
             const float* __restrict__ wscale_ptr,
             const float* __restrict__ bias,
             const float2* __restrict__ murs,
             const float* __restrict__ Sg,
             const float* __restrict__ Cb,
             int N, int K) {
  __shared__ unsigned short sA[128 * 64];
  __shared__ unsigned short sB[128 * 64];

  const int tid  = threadIdx.x;
  const int lane = tid & 63;
  const int wave = tid >> 6;
  const int wm   = wave & 1;   // 0..1
  const int wn   = wave >> 1;  // 0..1

  // XCD-aware remap of (bm, bn)
  const int nbx  = gridDim.x;                    // column tiles
  const int id   = blockIdx.y * nbx + blockIdx.x;
  const int xcd  = id & 7;
  const int slot = id >> 3;
  const int bandsPerXcd = gridDim.y >> 3;        // 8 for both GEMMs
  const int band = xcd * bandsPerXcd + slot / nbx;
  const int col  = slot - (slot / nbx) * nbx;
  const int bm   = band * 128;
  const int bn   = col * 128;

  // staging: thread t, round i: row 32i+(t>>3), stored chunk t&7,
  // global chunk (t&7)^((t>>3)&7)
  const int csw = (((tid & 7) ^ ((tid >> 3) & 7))) * 8;
  const unsigned short* Ab = A + (size_t)(bm + (tid >> 3)) * K + csw;
  const unsigned short* Bb = B + (size_t)(bn + (tid >> 3)) * K + csw;

  f32x4 acc[4][4] = {};

  // fragment read: row m = w*64 + i*16 + (lane&15); k-granule (half h) =
  // h*4 + (lane>>4); stored position = granule ^ (lane&7)
  const int rowA = (wm * 64 + (lane & 15)) * 64;
  const int rowB = (wn * 64 + (lane & 15)) * 64;
  const int p0 = ((0 + (lane >> 4)) ^ (lane & 7)) * 8;   // k-half 0
  const int p1 = ((4 + (lane >> 4)) ^ (lane & 7)) * 8;   // k-half 1

  for (int k0 = 0; k0 < K; k0 += 64) {
#pragma unroll
    for (int i = 0; i < 4; ++i) {
      gld16(Ab + (size_t)(32 * i) * K + k0, sA + i * 2048 + tid * 8);
      gld16(Bb + (size_t)(32 * i) * K + k0, sB + i * 2048 + tid * 8);
    }
    __syncthreads();

#pragma unroll
    for (int h = 0; h < 2; ++h) {
      const int ph = h ? p1 : p0;
      bf16x8 af[4], bfr[4];
#pragma unroll
      for (int i = 0; i < 4; ++i) af[i]  = *(const bf16x8*)(sA + rowA + i * 1024 + ph);
#pragma unroll
      for (int j = 0; j < 4; ++j) bfr[j] = *(const bf16x8*)(sB + rowB + j * 1024 + ph);
#pragma unroll
      for (int i = 0; i < 4; ++i)
#pragma unroll
        for (int j = 0; j < 4; ++j)
          acc[i][j] = __builtin_amdgcn_mfma_f32_16x16x32_bf16(af[i], bfr[j], acc[i][j], 0, 0, 0);
    }
    __syncthreads();
  }

  if (MODE == 1) {
    const float wscale = *wscale_ptr;
    float bv[4];
#pragma unroll
    for (int j = 0; j < 4; ++j) bv[j] = bias[bn + wn * 64 + j * 16 + (lane & 15)];
#pragma unroll
    for (int i = 0; i < 4; ++i) {
      const int m0 = bm + wm * 64 + i * 16 + ((lane >> 4) << 2);
#pragma unroll
      for (int j = 0; j < 4; ++j) {
        const int n = bn + wn * 64 + j * 16 + (lane & 15);
#pragma unroll
        for (int r = 0; r < 4; ++r) {
          float v = fast_gelu(acc[i][j][r] * wscale + bv[j]);
          ((unsigned short*)Cv)[(size_t)(m0 + r) * N + n] = f2bf(v);
        }
      }
    }
  } else {
    float sg[4], cb[4];
#pragma unroll
    for (int j = 0; j < 4; ++j) {
      const int n = bn + wn * 64 + j * 16 + (lane & 15);
      sg[j] = Sg[n];
      cb[j] = Cb[n];
    }
#pragma unroll
    for (int i = 0; i < 4; ++i) {
      const int m0 = bm + wm * 64 + i * 16 + ((lane >> 4) << 2);
#pragma unroll
      for (int r = 0; r < 4; ++r) {
        float2 ab = murs[m0 + r];
#pragma unroll
        for (int j = 0; j < 4; ++j) {
          const int n = bn + wn * 64 + j * 16 + (lane & 15);
          ((float*)Cv)[(size_t)(m0 + r) * N + n] = ab.x * acc[i][j][r] + ab.y * sg[j] + cb[j];
        }
      }
    }
  }
}

extern "C" void kernel_launch(void* const* d_in, const int* in_sizes, int n_in,
                              void* d_out, int out_size, void* d_ws, size_t ws_size,
                              hipStream_t stream) {
  const float* x     = (const float*)d_in[0];
  const float* g1    = (const float*)d_in[1];
  const float* b1v   = (const float*)d_in[2];
  const float* w1    = (const float*)d_in[3];
  const float* bias1 = (const float*)d_in[4];
  const float* g2    = (const float*)d_in[5];
  const float* b2v   = (const float*)d_in[6];
  const float* w2    = (const float*)d_in[7];
  const float* bias2 = (const float*)d_in[8];
  float* out = (float*)d_out;

  char* ws = (char*)d_ws;
  float* scal          = (float*)ws;                 // [0]=mean|w1| [1]=mean|w2| (clipped)
  float* part          = (float*)(ws + 64);          // 2048 partial sums
  unsigned short* q1   = (unsigned short*)(ws + 16384);   // 4096x1024 bf16
  unsigned short* q2   = q1 + 4194304;                    // 1024x4096 bf16 (g2-scaled)
  unsigned short* xn   = q2 + 4194304;                    // 8192x1024 bf16
  unsigned short* h    = xn + 8388608;                    // 8192x4096 bf16 (gelu out)
  float2* murs         = (float2*)(h + 33554432);         // 8192 x {a_m, b_m}
  float* Sg            = (float*)(murs + 8192);           // 1024
  float* Cb            = Sg + 1024;                       // 1024

  absum_kernel<<<2048, 256, 0, stream>>>(w1, w2, part);
  final_reduce<<<1, 256, 0, stream>>>(part, scal);
  quant_kernel<<<1536, 256, 0, stream>>>(w1, q1, w2, q2, scal, g2, b2v, bias2, Sg, Cb);
  ln1_kernel<<<8192, 256, 0, stream>>>(x, g1, b1v, xn);
  gemm_bt<1><<<dim3(HID / 128, MROWS / 128), 256, 0, stream>>>(
      xn, q1, h, scal + 0, bias1, nullptr, nullptr, nullptr, HID, DIM);
  rowstats_kernel<<<8192, 256, 0, stream>>>(h, scal, murs);
  gemm_bt<0><<<dim3(DIM / 128, MROWS / 128), 256, 0, stream>>>(
      h, q2, out, scal + 1, nullptr, murs, Sg, Cb, DIM, HID);
}

// Round 9
// 287.601 us; speedup vs baseline: 1.3796x; 1.0172x over previous
//
#include <hip/hip_runtime.h>
#include <cstdint>
#include <cstddef>

// Problem dims (fixed by reference): x [8,1024,1024] -> M=8192, dim=1024, hidden=4096
#define DIM   1024
#define HID   4096
#define MROWS 8192

typedef __attribute__((ext_vector_type(8))) __bf16 bf16x8;
typedef __attribute__((ext_vector_type(4))) float  f32x4;

__device__ __forceinline__ unsigned short f2bf(float f) {
  unsigned int u = __float_as_uint(f);
  u += 0x7fffu + ((u >> 16) & 1u);   // round-to-nearest-even
  return (unsigned short)(u >> 16);
}
__device__ __forceinline__ float bf2f(unsigned int lo16) {
  return __uint_as_float(lo16 << 16);
}

// tanh-form GELU: ~7 VALU instrs vs ~25 for erff; deviation from exact ~1e-3.
__device__ __forceinline__ float fast_gelu(float v) {
  float u = v * (0.79788456080286536f + 0.035677408136300125f * v * v);
  float e = __builtin_amdgcn_exp2f(u * 2.8853900817779268f);   // exp(2u)
  float r = __builtin_amdgcn_rcpf(e + 1.0f);
  return v - v * r;   // = v * e/(e+1) = 0.5 v (1+tanh(u))
}

// ---- async global->LDS, 16B per lane (m97 pattern) ----
__device__ __forceinline__ void gld16(const void* g, void* l) {
  auto* gp = reinterpret_cast<__attribute__((address_space(1))) unsigned int*>(
      reinterpret_cast<uintptr_t>(g));
  auto* lp = reinterpret_cast<__attribute__((address_space(3))) unsigned int*>(
      reinterpret_cast<uintptr_t>(l));
  __builtin_amdgcn_global_load_lds(gp, lp, 16, 0, 0);
}

// ---- block reduce (two values), 256 threads = 4 waves ----
__device__ __forceinline__ void block_reduce2(float& a, float& b, int tid) {
#pragma unroll
  for (int off = 32; off > 0; off >>= 1) {
    a += __shfl_xor(a, off, 64);
    b += __shfl_xor(b, off, 64);
  }
  __shared__ float red[8];
  if ((tid & 63) == 0) { red[tid >> 6] = a; red[4 + (tid >> 6)] = b; }
  __syncthreads();
  a = red[0] + red[1] + red[2] + red[3];
  b = red[4] + red[5] + red[6] + red[7];
}

// ---- stage 1: per-block partial sums of |w| (4096 floats per block) ----
// blocks 0..1023 -> w1, 1024..2047 -> w2 (both are 4M elements)
__global__ __launch_bounds__(256)
void absum_kernel(const float* __restrict__ w1, const float* __restrict__ w2,
                  float* __restrict__ part) {
  int tid = threadIdx.x;
  const float* w = (blockIdx.x < 1024) ? w1 : w2;
  int blk = blockIdx.x & 1023;
  const float4* base = (const float4*)w + (size_t)blk * 1024;
  float s = 0.f;
#pragma unroll
  for (int i = 0; i < 4; ++i) {
    float4 v = base[tid + i * 256];
    s += fabsf(v.x) + fabsf(v.y) + fabsf(v.z) + fabsf(v.w);
  }
#pragma unroll
  for (int off = 32; off > 0; off >>= 1) s += __shfl_xor(s, off, 64);
  __shared__ float red[4];
  if ((tid & 63) == 0) red[tid >> 6] = s;
  __syncthreads();
  if (tid == 0) part[blockIdx.x] = red[0] + red[1] + red[2] + red[3];
}

// ---- stage 2: final deterministic reduce -> clipped means for both weights ----
__global__ __launch_bounds__(256)
void final_reduce(const float* __restrict__ part, float* __restrict__ out) {
  int tid = threadIdx.x;
  float a = 0.f, b = 0.f;
  for (int i = tid; i < 1024; i += 256) { a += part[i]; b += part[1024 + i]; }
  block_reduce2(a, b, tid);
  if (tid == 0) {
    out[0] = fmaxf(a * (1.0f / 4194304.0f), 1e-5f);  // mean|w1| clipped
    out[1] = fmaxf(b * (1.0f / 4194304.0f), 1e-5f);  // mean|w2| clipped
  }
}

// ---- ternary quantize + folded-LN2 weight vectors, one kernel ----
// blocks 0..511:    q1 = clip(rint(w1/mean1)) as bf16 {-1,0,1} (grid-stride)
// blocks 512..1535: block owns w2 row d = bid-512:
//   q2[d][k] = clip(rint(w2/mean2)) * g2[k]   (LN2 gain folded into B)
//   Sg[d] = mean2 * sum_k g2[k]*t;  Cb[d] = mean2 * sum_k b2[k]*t + bias2[d]
__global__ __launch_bounds__(256)
void quant_kernel(const float* __restrict__ w1, unsigned short* __restrict__ q1,
                  const float* __restrict__ w2, unsigned short* __restrict__ q2,
                  const float* __restrict__ meanp, const float* __restrict__ g2,
                  const float* __restrict__ b2, const float* __restrict__ bias2,
                  float* __restrict__ Sg, float* __restrict__ Cb) {
  int bid = blockIdx.x, tid = threadIdx.x;
  if (bid < 512) {
    const int n4 = 1048576;
    float sc = 1.0f / meanp[0];
    int i = bid * 256 + tid;
    for (; i < n4; i += 512 * 256) {
      float4 v = ((const float4*)w1)[i];
      float t0 = fminf(fmaxf(rintf(v.x * sc), -1.f), 1.f);
      float t1 = fminf(fmaxf(rintf(v.y * sc), -1.f), 1.f);
      float t2 = fminf(fmaxf(rintf(v.z * sc), -1.f), 1.f);
      float t3 = fminf(fmaxf(rintf(v.w * sc), -1.f), 1.f);
      uint2 r;
      r.x = (unsigned)f2bf(t0) | ((unsigned)f2bf(t1) << 16);
      r.y = (unsigned)f2bf(t2) | ((unsigned)f2bf(t3) << 16);
      ((uint2*)q1)[i] = r;
    }
  } else {
    const int d = bid - 512;
    float sc = 1.0f / meanp[1];
    const float4* wr = (const float4*)(w2 + (size_t)d * HID);
    const float4* g4 = (const float4*)g2;
    const float4* b4 = (const float4*)b2;
    uint2* qr = (uint2*)(q2 + (size_t)d * HID);
    float s1 = 0.f, s2 = 0.f;
#pragma unroll
    for (int i = 0; i < 4; ++i) {
      int idx = tid + 256 * i;
      float4 wv = wr[idx], gv = g4[idx], bv = b4[idx];
      float t0 = fminf(fmaxf(rintf(wv.x * sc), -1.f), 1.f);
      float t1 = fminf(fmaxf(rintf(wv.y * sc), -1.f), 1.f);
      float t2 = fminf(fmaxf(rintf(wv.z * sc), -1.f), 1.f);
      float t3 = fminf(fmaxf(rintf(wv.w * sc), -1.f), 1.f);
      s1 += gv.x * t0 + gv.y * t1 + gv.z * t2 + gv.w * t3;
      s2 += bv.x * t0 + bv.y * t1 + bv.z * t2 + bv.w * t3;
      uint2 r;
      r.x = (unsigned)f2bf(t0 * gv.x) | ((unsigned)f2bf(t1 * gv.y) << 16);
      r.y = (unsigned)f2bf(t2 * gv.z) | ((unsigned)f2bf(t3 * gv.w) << 16);
      qr[idx] = r;
    }
    block_reduce2(s1, s2, tid);
    if (tid == 0) {
      float m = meanp[1];
      Sg[d] = m * s1;
      Cb[d] = m * s2 + bias2[d];
    }
  }
}

// ---- LN1: fp32 [8192,1024] -> bf16 normalized ----
__global__ __launch_bounds__(256)
void ln1_kernel(const float* __restrict__ x, const float* __restrict__ g,
                const float* __restrict__ b, unsigned short* __restrict__ out) {
  int tid = threadIdx.x;
  const float4* xr = (const float4*)(x + (size_t)blockIdx.x * DIM);
  float4 v = xr[tid];
  float s  = v.x + v.y + v.z + v.w;
  float ss = v.x * v.x + v.y * v.y + v.z * v.z + v.w * v.w;
  block_reduce2(s, ss, tid);
  float mu  = s * (1.0f / DIM);
  float var = ss * (1.0f / DIM) - mu * mu;
  float rs  = rsqrtf(var + 1e-5f);
  float4 gg = ((const float4*)g)[tid];
  float4 bb = ((const float4*)b)[tid];
  uint2 r;
  r.x = (unsigned)f2bf((v.x - mu) * rs * gg.x + bb.x) |
        ((unsigned)f2bf((v.y - mu) * rs * gg.y + bb.y) << 16);
  r.y = (unsigned)f2bf((v.z - mu) * rs * gg.z + bb.z) |
        ((unsigned)f2bf((v.w - mu) * rs * gg.w + bb.w) << 16);
  *(uint2*)(out + (size_t)blockIdx.x * DIM + tid * 4) = r;
}

// ---- row stats of h (read-only) -> per-row (a_m, b_m) for folded LN2 ----
// One block per row: read 4096 bf16 (8 KB), block-reduce, write murs[m].
__global__ __launch_bounds__(256)
void rowstats_kernel(const unsigned short* __restrict__ h,
                     const float* __restrict__ meanp,
                     float2* __restrict__ murs) {
  int tid = threadIdx.x;
  const unsigned short* hr = h + (size_t)blockIdx.x * HID;
  uint4 pa = ((const uint4*)hr)[tid];
  uint4 pb = ((const uint4*)hr)[tid + 256];
  float s = 0.f, ss = 0.f;
  {
    const unsigned int* pu = (const unsigned int*)&pa;
#pragma unroll
    for (int j = 0; j < 4; ++j) {
      float lo = bf2f(pu[j] & 0xffffu);
      float hi = __uint_as_float(pu[j] & 0xffff0000u);
      s += lo + hi; ss += lo * lo + hi * hi;
    }
    pu = (const unsigned int*)&pb;
#pragma unroll
    for (int j = 0; j < 4; ++j) {
      float lo = bf2f(pu[j] & 0xffffu);
      float hi = __uint_as_float(pu[j] & 0xffff0000u);
      s += lo + hi; ss += lo * lo + hi * hi;
    }
  }
  block_reduce2(s, ss, tid);
  if (tid == 0) {
    float mu  = s * (1.0f / HID);
    float var = ss * (1.0f / HID) - mu * mu;
    float rs  = rsqrtf(var + 1e-5f);
    murs[blockIdx.x] = make_float2(rs * meanp[1], -rs * mu);
  }
}

// ---- GEMM C[m,n] = sum_k A[m,k]*B[n,k], fused epilogues ----
// A: bf16 [M,KK] row-major; B: bf16 [N,KK] row-major. KK is COMPILE-TIME so
// the K-loop addressing strength-reduces to constant increments (R8: GEMM1
// VALUBusy 56% was partly runtime-K address math).
// Tile MT x 128 (MT=128 or 64), BK=64, 256 thr = 4 waves; wave grid 2x2:
// wave (wm,wn) owns rows wm*(MT/2)..+(MT/2), cols wn*64..+64.
// MT=64 for GEMM2: N=1024 gives only 8 col tiles; 64-row bands double the
// block count 512->1024 (2->4 blocks/CU) to fix R8's 19.5% occupancy.
// LDS XOR-granule swizzle: 16B chunk c of row r at position c^(r&7) (R2).
// XCD swizzle: XCD (id%8) owns contiguous bands w/ all col tiles (R4).
// MODE 1 (GEMM1): v = gelu(acc*wscale + bias[n]); store bf16.
// MODE 0 (GEMM2): LN2 folded: out = a_m*acc + b_m*Sg[n] + Cb[n], fp32 store.
template <int MODE, int MT, int KK>
__global__ __launch_bounds__(256)
void gemm_bt(const unsigned short* __restrict__ A,
             const unsigned short* __restrict__ B,
             void* __restrict__ Cv,
             const float* __restrict__ wscale_ptr,
             const float* __restrict__ bias,
             const float2* __restrict__ murs,
             const float* __restrict__ Sg,
             const float* __restrict__ Cb,
             int N) {
  constexpr int IT = MT / 32;            // i-tiles per wave == A staging rounds
  __shared__ unsigned short sA[MT * 64];
  __shared__ unsigned short sB[128 * 64];

  const int tid  = threadIdx.x;
  const int lane = tid & 63;
  const int wave = tid >> 6;
  const int wm   = wave & 1;   // 0..1
  const int wn   = wave >> 1;  // 0..1

  // XCD-aware remap of (bm, bn)
  const int nbx  = gridDim.x;                    // column tiles
  const int id   = blockIdx.y * nbx + blockIdx.x;
  const int xcd  = id & 7;
  const int slot = id >> 3;
  const int bandsPerXcd = gridDim.y >> 3;
  const int band = xcd * bandsPerXcd + slot / nbx;
  const int col  = slot - (slot / nbx) * nbx;
  const int bm   = band * MT;
  const int bn   = col * 128;

  // staging: thread t, round i: row 32i+(t>>3), stored chunk t&7,
  // global chunk (t&7)^((t>>3)&7)
  const int csw = (((tid & 7) ^ ((tid >> 3) & 7))) * 8;
  const unsigned short* Ab = A + (size_t)(bm + (tid >> 3)) * KK + csw;
  const unsigned short* Bb = B + (size_t)(bn + (tid >> 3)) * KK + csw;

  f32x4 acc[IT][4] = {};

  // fragment read: row m = wm*(MT/2) + i*16 + (lane&15); k-granule (half h) =
  // h*4 + (lane>>4); stored position = granule ^ (lane&7)
  const int rowA = (wm * (MT / 2) + (lane & 15)) * 64;
  const int rowB = (wn * 64 + (lane & 15)) * 64;
  const int p0 = ((0 + (lane >> 4)) ^ (lane & 7)) * 8;   // k-half 0
  const int p1 = ((4 + (lane >> 4)) ^ (lane & 7)) * 8;   // k-half 1

  for (int k0 = 0; k0 < KK; k0 += 64) {
#pragma unroll
    for (int i = 0; i < IT; ++i)
      gld16(Ab + (size_t)(32 * i) * KK + k0, sA + i * 2048 + tid * 8);
#pragma unroll
    for (int i = 0; i < 4; ++i)
      gld16(Bb + (size_t)(32 * i) * KK + k0, sB + i * 2048 + tid * 8);
    __syncthreads();

#pragma unroll
    for (int h = 0; h < 2; ++h) {
      const int ph = h ? p1 : p0;
      bf16x8 af[IT], bfr[4];
#pragma unroll
      for (int i = 0; i < IT; ++i) af[i] = *(const bf16x8*)(sA + rowA + i * 1024 + ph);
#pragma unroll
      for (int j = 0; j < 4; ++j) bfr[j] = *(const bf16x8*)(sB + rowB + j * 1024 + ph);
#pragma unroll
      for (int i = 0; i < IT; ++i)
#pragma unroll
        for (int j = 0; j < 4; ++j)
          acc[i][j] = __builtin_amdgcn_mfma_f32_16x16x32_bf16(af[i], bfr[j], acc[i][j], 0, 0, 0);
    }
    __syncthreads();
  }

  if (MODE == 1) {
    const float wscale = *wscale_ptr;
    float bv[4];
#pragma unroll
    for (int j = 0; j < 4; ++j) bv[j] = bias[bn + wn * 64 + j * 16 + (lane & 15)];
#pragma unroll
    for (int i = 0; i < IT; ++i) {
      const int m0 = bm + wm * (MT / 2) + i * 16 + ((lane >> 4) << 2);
#pragma unroll
      for (int j = 0; j < 4; ++j) {
        const int n = bn + wn * 64 + j * 16 + (lane & 15);
#pragma unroll
        for (int r = 0; r < 4; ++r) {
          float v = fast_gelu(acc[i][j][r] * wscale + bv[j]);
          ((unsigned short*)Cv)[(size_t)(m0 + r) * N + n] = f2bf(v);
        }
      }
    }
  } else {
    float sg[4], cb[4];
#pragma unroll
    for (int j = 0; j < 4; ++j) {
      const int n = bn + wn * 64 + j * 16 + (lane & 15);
      sg[j] = Sg[n];
      cb[j] = Cb[n];
    }
#pragma unroll
    for (int i = 0; i < IT; ++i) {
      const int m0 = bm + wm * (MT / 2) + i * 16 + ((lane >> 4) << 2);
#pragma unroll
      for (int r = 0; r < 4; ++r) {
        float2 ab = murs[m0 + r];
#pragma unroll
        for (int j = 0; j < 4; ++j) {
          const int n = bn + wn * 64 + j * 16 + (lane & 15);
          ((float*)Cv)[(size_t)(m0 + r) * N + n] = ab.x * acc[i][j][r] + ab.y * sg[j] + cb[j];
        }
      }
    }
  }
}

extern "C" void kernel_launch(void* const* d_in, const int* in_sizes, int n_in,
                              void* d_out, int out_size, void* d_ws, size_t ws_size,
                              hipStream_t stream) {
  const float* x     = (const float*)d_in[0];
  const float* g1    = (const float*)d_in[1];
  const float* b1v   = (const float*)d_in[2];
  const float* w1    = (const float*)d_in[3];
  const float* bias1 = (const float*)d_in[4];
  const float* g2    = (const float*)d_in[5];
  const float* b2v   = (const float*)d_in[6];
  const float* w2    = (const float*)d_in[7];
  const float* bias2 = (const float*)d_in[8];
  float* out = (float*)d_out;

  char* ws = (char*)d_ws;
  float* scal          = (float*)ws;                 // [0]=mean|w1| [1]=mean|w2| (clipped)
  float* part          = (float*)(ws + 64);          // 2048 partial sums
  unsigned short* q1   = (unsigned short*)(ws + 16384);   // 4096x1024 bf16
  unsigned short* q2   = q1 + 4194304;                    // 1024x4096 bf16 (g2-scaled)
  unsigned short* xn   = q2 + 4194304;                    // 8192x1024 bf16
  unsigned short* h    = xn + 8388608;                    // 8192x4096 bf16 (gelu out)
  float2* murs         = (float2*)(h + 33554432);         // 8192 x {a_m, b_m}
  float* Sg            = (float*)(murs + 8192);           // 1024
  float* Cb            = Sg + 1024;                       // 1024

  absum_kernel<<<2048, 256, 0, stream>>>(w1, w2, part);
  final_reduce<<<1, 256, 0, stream>>>(part, scal);
  quant_kernel<<<1536, 256, 0, stream>>>(w1, q1, w2, q2, scal, g2, b2v, bias2, Sg, Cb);
  ln1_kernel<<<8192, 256, 0, stream>>>(x, g1, b1v, xn);
  gemm_bt<1, 128, DIM><<<dim3(HID / 128, MROWS / 128), 256, 0, stream>>>(
      xn, q1, h, scal + 0, bias1, nullptr, nullptr, nullptr, HID);
  rowstats_kernel<<<8192, 256, 0, stream>>>(h, scal, murs);
  gemm_bt<0, 64, HID><<<dim3(DIM / 128, MROWS / 64), 256, 0, stream>>>(
      h, q2, out, scal + 1, nullptr, murs, Sg, Cb, DIM);
}

// Round 10
// 283.878 us; speedup vs baseline: 1.3977x; 1.0131x over previous
//
#include <hip/hip_runtime.h>
#include <cstdint>
#include <cstddef>

// Problem dims (fixed by reference): x [8,1024,1024] -> M=8192, dim=1024, hidden=4096
#define DIM   1024
#define HID   4096
#define MROWS 8192

typedef __attribute__((ext_vector_type(8))) __bf16 bf16x8;
typedef __attribute__((ext_vector_type(4))) float  f32x4;

__device__ __forceinline__ unsigned short f2bf(float f) {
  unsigned int u = __float_as_uint(f);
  u += 0x7fffu + ((u >> 16) & 1u);   // round-to-nearest-even
  return (unsigned short)(u >> 16);
}
__device__ __forceinline__ float bf2f(unsigned int lo16) {
  return __uint_as_float(lo16 << 16);
}

// tanh-form GELU: ~7 VALU instrs vs ~25 for erff; deviation from exact ~1e-3.
__device__ __forceinline__ float fast_gelu(float v) {
  float u = v * (0.79788456080286536f + 0.035677408136300125f * v * v);
  float e = __builtin_amdgcn_exp2f(u * 2.8853900817779268f);   // exp(2u)
  float r = __builtin_amdgcn_rcpf(e + 1.0f);
  return v - v * r;   // = v * e/(e+1) = 0.5 v (1+tanh(u))
}

// ---- async global->LDS, 16B per lane (m97 pattern) ----
__device__ __forceinline__ void gld16(const void* g, void* l) {
  auto* gp = reinterpret_cast<__attribute__((address_space(1))) unsigned int*>(
      reinterpret_cast<uintptr_t>(g));
  auto* lp = reinterpret_cast<__attribute__((address_space(3))) unsigned int*>(
      reinterpret_cast<uintptr_t>(l));
  __builtin_amdgcn_global_load_lds(gp, lp, 16, 0, 0);
}

// ---- block reduce (two values), 256 threads = 4 waves ----
// Leading __syncthreads makes back-to-back calls safe (shared red[] reuse).
__device__ __forceinline__ void block_reduce2(float& a, float& b, int tid) {
  __shared__ float red[8];
  __syncthreads();
#pragma unroll
  for (int off = 32; off > 0; off >>= 1) {
    a += __shfl_xor(a, off, 64);
    b += __shfl_xor(b, off, 64);
  }
  if ((tid & 63) == 0) { red[tid >> 6] = a; red[4 + (tid >> 6)] = b; }
  __syncthreads();
  a = red[0] + red[1] + red[2] + red[3];
  b = red[4] + red[5] + red[6] + red[7];
}

// ---- prep: |w| partial sums AND LN1, one dispatch (independent work) ----
// blocks 0..1023:    absum partials of w1 (4096 floats each) -> part[bid]
// blocks 1024..2047: absum partials of w2 -> part[bid]
// blocks 2048..10239: LN1 row (bid-2048): fp32 [1024] -> bf16 normalized
__global__ __launch_bounds__(256)
void prep_kernel(const float* __restrict__ w1, const float* __restrict__ w2,
                 float* __restrict__ part,
                 const float* __restrict__ x, const float* __restrict__ g,
                 const float* __restrict__ b, unsigned short* __restrict__ xn) {
  int tid = threadIdx.x;
  int bid = blockIdx.x;
  if (bid < 2048) {
    const float* w = (bid < 1024) ? w1 : w2;
    int blk = bid & 1023;
    const float4* base = (const float4*)w + (size_t)blk * 1024;
    float s = 0.f;
#pragma unroll
    for (int i = 0; i < 4; ++i) {
      float4 v = base[tid + i * 256];
      s += fabsf(v.x) + fabsf(v.y) + fabsf(v.z) + fabsf(v.w);
    }
#pragma unroll
    for (int off = 32; off > 0; off >>= 1) s += __shfl_xor(s, off, 64);
    __shared__ float red[4];
    if ((tid & 63) == 0) red[tid >> 6] = s;
    __syncthreads();
    if (tid == 0) part[bid] = red[0] + red[1] + red[2] + red[3];
  } else {
    const int row = bid - 2048;
    const float4* xr = (const float4*)(x + (size_t)row * DIM);
    float4 v = xr[tid];
    float s  = v.x + v.y + v.z + v.w;
    float ss = v.x * v.x + v.y * v.y + v.z * v.z + v.w * v.w;
    block_reduce2(s, ss, tid);
    float mu  = s * (1.0f / DIM);
    float var = ss * (1.0f / DIM) - mu * mu;
    float rs  = rsqrtf(var + 1e-5f);
    float4 gg = ((const float4*)g)[tid];
    float4 bb = ((const float4*)b)[tid];
    uint2 r;
    r.x = (unsigned)f2bf((v.x - mu) * rs * gg.x + bb.x) |
          ((unsigned)f2bf((v.y - mu) * rs * gg.y + bb.y) << 16);
    r.y = (unsigned)f2bf((v.z - mu) * rs * gg.z + bb.z) |
          ((unsigned)f2bf((v.w - mu) * rs * gg.w + bb.w) << 16);
    *(uint2*)(xn + (size_t)row * DIM + tid * 4) = r;
  }
}

// ---- ternary quantize + folded-LN2 weight vectors; inlines the mean reduce ----
// Every block redundantly reduces its half of part[] (4KB, L2-hot, deterministic
// -> bitwise-identical mean in all blocks; removes the serializing 1-block
// final_reduce dispatch, ~10us dispatch overhead each per R9 accounting).
// blocks 0..511:    q1 = clip(rint(w1/mean1)) as bf16 {-1,0,1} (grid-stride);
//                   block 0 tid 0 publishes scal[0]=mean1.
// blocks 512..1535: block owns w2 row d = bid-512:
//   q2[d][k] = clip(rint(w2/mean2)) * g2[k]   (LN2 gain folded into B)
//   Sg[d] = mean2*sum_k g2[k]*t;  Cb[d] = mean2*sum_k b2[k]*t + bias2[d]
//   block 512 tid 0 publishes scal[1]=mean2.
__global__ __launch_bounds__(256)
void quant_kernel(const float* __restrict__ part,
                  const float* __restrict__ w1, unsigned short* __restrict__ q1,
                  const float* __restrict__ w2, unsigned short* __restrict__ q2,
                  const float* __restrict__ g2, const float* __restrict__ b2,
                  const float* __restrict__ bias2,
                  float* __restrict__ Sg, float* __restrict__ Cb,
                  float* __restrict__ scal) {
  int bid = blockIdx.x, tid = threadIdx.x;
  // inline mean of the relevant weight: reduce 1024 partials (float4 x 256)
  const float4* psrc = (const float4*)(part + ((bid < 512) ? 0 : 1024));
  float4 pv = psrc[tid];
  float a = pv.x + pv.y + pv.z + pv.w, dummy = 0.f;
  block_reduce2(a, dummy, tid);
  float mean = fmaxf(a * (1.0f / 4194304.0f), 1e-5f);
  float sc = 1.0f / mean;

  if (bid < 512) {
    if (bid == 0 && tid == 0) scal[0] = mean;
    const int n4 = 1048576;
    int i = bid * 256 + tid;
    for (; i < n4; i += 512 * 256) {
      float4 v = ((const float4*)w1)[i];
      float t0 = fminf(fmaxf(rintf(v.x * sc), -1.f), 1.f);
      float t1 = fminf(fmaxf(rintf(v.y * sc), -1.f), 1.f);
      float t2 = fminf(fmaxf(rintf(v.z * sc), -1.f), 1.f);
      float t3 = fminf(fmaxf(rintf(v.w * sc), -1.f), 1.f);
      uint2 r;
      r.x = (unsigned)f2bf(t0) | ((unsigned)f2bf(t1) << 16);
      r.y = (unsigned)f2bf(t2) | ((unsigned)f2bf(t3) << 16);
      ((uint2*)q1)[i] = r;
    }
  } else {
    const int d = bid - 512;
    if (d == 0 && tid == 0) scal[1] = mean;
    const float4* wr = (const float4*)(w2 + (size_t)d * HID);
    const float4* g4 = (const float4*)g2;
    const float4* b4 = (const float4*)b2;
    uint2* qr = (uint2*)(q2 + (size_t)d * HID);
    float s1 = 0.f, s2 = 0.f;
#pragma unroll
    for (int i = 0; i < 4; ++i) {
      int idx = tid + 256 * i;
      float4 wv = wr[idx], gv = g4[idx], bv = b4[idx];
      float t0 = fminf(fmaxf(rintf(wv.x * sc), -1.f), 1.f);
      float t1 = fminf(fmaxf(rintf(wv.y * sc), -1.f), 1.f);
      float t2 = fminf(fmaxf(rintf(wv.z * sc), -1.f), 1.f);
      float t3 = fminf(fmaxf(rintf(wv.w * sc), -1.f), 1.f);
      s1 += gv.x * t0 + gv.y * t1 + gv.z * t2 + gv.w * t3;
      s2 += bv.x * t0 + bv.y * t1 + bv.z * t2 + bv.w * t3;
      uint2 r;
      r.x = (unsigned)f2bf(t0 * gv.x) | ((unsigned)f2bf(t1 * gv.y) << 16);
      r.y = (unsigned)f2bf(t2 * gv.z) | ((unsigned)f2bf(t3 * gv.w) << 16);
      qr[idx] = r;
    }
    block_reduce2(s1, s2, tid);
    if (tid == 0) {
      Sg[d] = mean * s1;
      Cb[d] = mean * s2 + bias2[d];
    }
  }
}

// ---- row stats of h (read-only) -> per-row (a_m, b_m) for folded LN2 ----
// One block per row: read 4096 bf16 (8 KB), block-reduce, write murs[m].
__global__ __launch_bounds__(256)
void rowstats_kernel(const unsigned short* __restrict__ h,
                     const float* __restrict__ meanp,
                     float2* __restrict__ murs) {
  int tid = threadIdx.x;
  const unsigned short* hr = h + (size_t)blockIdx.x * HID;
  uint4 pa = ((const uint4*)hr)[tid];
  uint4 pb = ((const uint4*)hr)[tid + 256];
  float s = 0.f, ss = 0.f;
  {
    const unsigned int* pu = (const unsigned int*)&pa;
#pragma unroll
    for (int j = 0; j < 4; ++j) {
      float lo = bf2f(pu[j] & 0xffffu);
      float hi = __uint_as_float(pu[j] & 0xffff0000u);
      s += lo + hi; ss += lo * lo + hi * hi;
    }
    pu = (const unsigned int*)&pb;
#pragma unroll
    for (int j = 0; j < 4; ++j) {
      float lo = bf2f(pu[j] & 0xffffu);
      float hi = __uint_as_float(pu[j] & 0xffff0000u);
      s += lo + hi; ss += lo * lo + hi * hi;
    }
  }
  block_reduce2(s, ss, tid);
  if (tid == 0) {
    float mu  = s * (1.0f / HID);
    float var = ss * (1.0f / HID) - mu * mu;
    float rs  = rsqrtf(var + 1e-5f);
    murs[blockIdx.x] = make_float2(rs * meanp[1], -rs * mu);
  }
}

// ---- GEMM C[m,n] = sum_k A[m,k]*B[n,k], fused epilogues (unchanged R9) ----
// A: bf16 [M,KK] row-major; B: bf16 [N,KK] row-major. KK compile-time
// (strength-reduced addressing; R9: VALUBusy 56->34%).
// Tile MT x 128, BK=64, 256 thr = 4 waves (2x2); MT=64 for GEMM2 (block count).
// LDS XOR-granule swizzle (R2: conflicts 8.4M->0); XCD band swizzle (R4:
// FETCH 286->158MB). MODE 1: gelu+bf16 store. MODE 0: folded LN2, fp32 store.
template <int MODE, int MT, int KK>
__global__ __launch_bounds__(256)
void gemm_bt(const unsigned short* __restrict__ A,
             const unsigned short* __restrict__ B,
             void* __restrict__ Cv,
             const float* __restrict__ wscale_ptr,
             const float* __restrict__ bias,
             const float2* __restrict__ murs,
             const float* __restrict__ Sg,
             const float* __restrict__ Cb,
             int N) {
  constexpr int IT = MT / 32;            // i-tiles per wave == A staging rounds
  __shared__ unsigned short sA[MT * 64];
  __shared__ unsigned short sB[128 * 64];

  const int tid  = threadIdx.x;
  const int lane = tid & 63;
  const int wave = tid >> 6;
  const int wm   = wave & 1;   // 0..1
  const int wn   = wave >> 1;  // 0..1

  // XCD-aware remap of (bm, bn)
  const int nbx  = gridDim.x;                    // column tiles
  const int id   = blockIdx.y * nbx + blockIdx.x;
  const int xcd  = id & 7;
  const int slot = id >> 3;
  const int bandsPerXcd = gridDim.y >> 3;
  const int band = xcd * bandsPerXcd + slot / nbx;
  const int col  = slot - (slot / nbx) * nbx;
  const int bm   = band * MT;
  const int bn   = col * 128;

  // staging: thread t, round i: row 32i+(t>>3), stored chunk t&7,
  // global chunk (t&7)^((t>>3)&7)
  const int csw = (((tid & 7) ^ ((tid >> 3) & 7))) * 8;
  const unsigned short* Ab = A + (size_t)(bm + (tid >> 3)) * KK + csw;
  const unsigned short* Bb = B + (size_t)(bn + (tid >> 3)) * KK + csw;

  f32x4 acc[IT][4] = {};

  // fragment read: row m = wm*(MT/2) + i*16 + (lane&15); k-granule (half h) =
  // h*4 + (lane>>4); stored position = granule ^ (lane&7)
  const int rowA = (wm * (MT / 2) + (lane & 15)) * 64;
  const int rowB = (wn * 64 + (lane & 15)) * 64;
  const int p0 = ((0 + (lane >> 4)) ^ (lane & 7)) * 8;   // k-half 0
  const int p1 = ((4 + (lane >> 4)) ^ (lane & 7)) * 8;   // k-half 1

  for (int k0 = 0; k0 < KK; k0 += 64) {
#pragma unroll
    for (int i = 0; i < IT; ++i)
      gld16(Ab + (size_t)(32 * i) * KK + k0, sA + i * 2048 + tid * 8);
#pragma unroll
    for (int i = 0; i < 4; ++i)
      gld16(Bb + (size_t)(32 * i) * KK + k0, sB + i * 2048 + tid * 8);
    __syncthreads();

#pragma unroll
    for (int h = 0; h < 2; ++h) {
      const int ph = h ? p1 : p0;
      bf16x8 af[IT], bfr[4];
#pragma unroll
      for (int i = 0; i < IT; ++i) af[i] = *(const bf16x8*)(sA + rowA + i * 1024 + ph);
#pragma unroll
      for (int j = 0; j < 4; ++j) bfr[j] = *(const bf16x8*)(sB + rowB + j * 1024 + ph);
#pragma unroll
      for (int i = 0; i < IT; ++i)
#pragma unroll
        for (int j = 0; j < 4; ++j)
          acc[i][j] = __builtin_amdgcn_mfma_f32_16x16x32_bf16(af[i], bfr[j], acc[i][j], 0, 0, 0);
    }
    __syncthreads();
  }

  if (MODE == 1) {
    const float wscale = *wscale_ptr;
    float bv[4];
#pragma unroll
    for (int j = 0; j < 4; ++j) bv[j] = bias[bn + wn * 64 + j * 16 + (lane & 15)];
#pragma unroll
    for (int i = 0; i < IT; ++i) {
      const int m0 = bm + wm * (MT / 2) + i * 16 + ((lane >> 4) << 2);
#pragma unroll
      for (int j = 0; j < 4; ++j) {
        const int n = bn + wn * 64 + j * 16 + (lane & 15);
#pragma unroll
        for (int r = 0; r < 4; ++r) {
          float v = fast_gelu(acc[i][j][r] * wscale + bv[j]);
          ((unsigned short*)Cv)[(size_t)(m0 + r) * N + n] = f2bf(v);
        }
      }
    }
  } else {
    float sg[4], cb[4];
#pragma unroll
    for (int j = 0; j < 4; ++j) {
      const int n = bn + wn * 64 + j * 16 + (lane & 15);
      sg[j] = Sg[n];
      cb[j] = Cb[n];
    }
#pragma unroll
    for (int i = 0; i < IT; ++i) {
      const int m0 = bm + wm * (MT / 2) + i * 16 + ((lane >> 4) << 2);
#pragma unroll
      for (int r = 0; r < 4; ++r) {
        float2 ab = murs[m0 + r];
#pragma unroll
        for (int j = 0; j < 4; ++j) {
          const int n = bn + wn * 64 + j * 16 + (lane & 15);
          ((float*)Cv)[(size_t)(m0 + r) * N + n] = ab.x * acc[i][j][r] + ab.y * sg[j] + cb[j];
        }
      }
    }
  }
}

extern "C" void kernel_launch(void* const* d_in, const int* in_sizes, int n_in,
                              void* d_out, int out_size, void* d_ws, size_t ws_size,
                              hipStream_t stream) {
  const float* x     = (const float*)d_in[0];
  const float* g1    = (const float*)d_in[1];
  const float* b1v   = (const float*)d_in[2];
  const float* w1    = (const float*)d_in[3];
  const float* bias1 = (const float*)d_in[4];
  const float* g2    = (const float*)d_in[5];
  const float* b2v   = (const float*)d_in[6];
  const float* w2    = (const float*)d_in[7];
  const float* bias2 = (const float*)d_in[8];
  float* out = (float*)d_out;

  char* ws = (char*)d_ws;
  float* scal          = (float*)ws;                 // [0]=mean|w1| [1]=mean|w2| (clipped)
  float* part          = (float*)(ws + 64);          // 2048 partial sums
  unsigned short* q1   = (unsigned short*)(ws + 16384);   // 4096x1024 bf16
  unsigned short* q2   = q1 + 4194304;                    // 1024x4096 bf16 (g2-scaled)
  unsigned short* xn   = q2 + 4194304;                    // 8192x1024 bf16
  unsigned short* h    = xn + 8388608;                    // 8192x4096 bf16 (gelu out)
  float2* murs         = (float2*)(h + 33554432);         // 8192 x {a_m, b_m}
  float* Sg            = (float*)(murs + 8192);           // 1024
  float* Cb            = Sg + 1024;                       // 1024

  // 5 dispatches (R9 had 7; ~10us overhead each per R2/R9 accounting)
  prep_kernel<<<10240, 256, 0, stream>>>(w1, w2, part, x, g1, b1v, xn);
  quant_kernel<<<1536, 256, 0, stream>>>(part, w1, q1, w2, q2, g2, b2v, bias2, Sg, Cb, scal);
  gemm_bt<1, 128, DIM><<<dim3(HID / 128, MROWS / 128), 256, 0, stream>>>(
      xn, q1, h, scal + 0, bias1, nullptr, nullptr, nullptr, HID);
  rowstats_kernel<<<8192, 256, 0, stream>>>(h, scal, murs);
  gemm_bt<0, 64, HID><<<dim3(DIM / 128, MROWS / 64), 256, 0, stream>>>(
      h, q2, out, scal + 1, nullptr, murs, Sg, Cb, DIM);
}